// Round 1
// baseline (1307.582 us; speedup 1.0000x reference)
//
#include <hip/hip_runtime.h>
#include <math.h>

#define N_NODES 100000
#define N_EDGES 3200000
#define F_IN    1024
#define HID     16
#define N_CLS   40

// ---------------- GEMM1: Y = x @ [W1[0] | W1[1] | root1]  (M=100000,K=1024,N=48)
#define BM 128
#define BK 32
#define BN 48
#define XSTR 130   // padded stride for transposed X tile (reduces bank conflicts)

__global__ __launch_bounds__(256) void gemm1(const float* __restrict__ x,
                                             const float* __restrict__ W1,
                                             const float* __restrict__ root1,
                                             float* __restrict__ y01,   // (N,32): [y0|y1]
                                             float* __restrict__ xr)    // (N,16)
{
    __shared__ float Xs[BK * XSTR];
    __shared__ float Ws[BK * BN];
    const int tid = threadIdx.x;
    const int block_row = blockIdx.x * BM;
    const int tr = tid & 31;   // 32 row groups
    const int tc = tid >> 5;   // 8 col groups
    const int r0 = tr * 4;     // 4 rows per thread
    const int c0 = tc * 6;     // 6 cols per thread

    float acc[4][6];
#pragma unroll
    for (int i = 0; i < 4; ++i)
#pragma unroll
        for (int j = 0; j < 6; ++j) acc[i][j] = 0.f;

    for (int kb = 0; kb < F_IN; kb += BK) {
        __syncthreads();
        // stage X tile (transposed): 128 rows x 32 k
#pragma unroll
        for (int pass = 0; pass < 4; ++pass) {
            int rowL = pass * 32 + (tid >> 3);
            int gr = block_row + rowL;
            int k0 = (tid & 7) * 4;
            float4 f4 = make_float4(0.f, 0.f, 0.f, 0.f);
            if (gr < N_NODES)
                f4 = *(const float4*)(x + (size_t)gr * F_IN + kb + k0);
            Xs[(k0 + 0) * XSTR + rowL] = f4.x;
            Xs[(k0 + 1) * XSTR + rowL] = f4.y;
            Xs[(k0 + 2) * XSTR + rowL] = f4.z;
            Xs[(k0 + 3) * XSTR + rowL] = f4.w;
        }
        // stage W tile: 32 k x 48 cols  (cols: 0-15 W1[0], 16-31 W1[1], 32-47 root1)
        {
            int kk = tid >> 3, g = tid & 7;
            const float* w10 = W1 + (size_t)(kb + kk) * HID;
            const float* w11 = W1 + (size_t)F_IN * HID + (size_t)(kb + kk) * HID;
            const float* rt  = root1 + (size_t)(kb + kk) * HID;
#pragma unroll
            for (int j = 0; j < 6; ++j) {
                int c = g * 6 + j;
                float v = (c < 16) ? w10[c] : ((c < 32) ? w11[c - 16] : rt[c - 32]);
                Ws[kk * BN + c] = v;
            }
        }
        __syncthreads();
#pragma unroll 8
        for (int k = 0; k < BK; ++k) {
            float xv[4], wv[6];
#pragma unroll
            for (int i = 0; i < 4; ++i) xv[i] = Xs[k * XSTR + r0 + i];
#pragma unroll
            for (int j = 0; j < 6; ++j) wv[j] = Ws[k * BN + c0 + j];
#pragma unroll
            for (int i = 0; i < 4; ++i)
#pragma unroll
                for (int j = 0; j < 6; ++j) acc[i][j] += xv[i] * wv[j];
        }
    }
    // epilogue: cols 0..31 -> y01, cols 32..47 -> xr
#pragma unroll
    for (int i = 0; i < 4; ++i) {
        int r = block_row + r0 + i;
        if (r >= N_NODES) break;
#pragma unroll
        for (int j = 0; j < 6; ++j) {
            int c = c0 + j;
            if (c < 32) y01[(size_t)r * 32 + c] = acc[i][j];
            else        xr[(size_t)r * 16 + (c - 32)] = acc[i][j];
        }
    }
}

// ---------------- CSR build
__global__ void hist_k(const int* __restrict__ ei, int* __restrict__ counts) {
    int e = blockIdx.x * 256 + threadIdx.x;
    if (e < N_EDGES) atomicAdd(&counts[ei[N_EDGES + e]], 1);
}

__global__ __launch_bounds__(256) void scan1_k(const int* __restrict__ counts,
                                               int* __restrict__ rowptr,
                                               int* __restrict__ partials) {
    __shared__ int sdata[256];
    int t = threadIdx.x;
    int base = blockIdx.x * 1024 + t * 4;
    int v[4];
#pragma unroll
    for (int i = 0; i < 4; ++i) v[i] = (base + i < N_NODES) ? counts[base + i] : 0;
    int tsum = v[0] + v[1] + v[2] + v[3];
    sdata[t] = tsum;
    __syncthreads();
    for (int o = 1; o < 256; o <<= 1) {
        int xv = (t >= o) ? sdata[t - o] : 0;
        __syncthreads();
        sdata[t] += xv;
        __syncthreads();
    }
    int run = sdata[t] - tsum;  // exclusive within block
#pragma unroll
    for (int i = 0; i < 4; ++i) {
        if (base + i < N_NODES) rowptr[base + i] = run;
        run += v[i];
    }
    if (t == 255) partials[blockIdx.x] = sdata[255];
}

__global__ void scan2_k(int* __restrict__ partials, int nb) {
    __shared__ int s[128];
    int t = threadIdx.x;
    int v = (t < nb) ? partials[t] : 0;
    s[t] = v;
    __syncthreads();
    for (int o = 1; o < 128; o <<= 1) {
        int xv = (t >= o) ? s[t - o] : 0;
        __syncthreads();
        s[t] += xv;
        __syncthreads();
    }
    if (t < nb) partials[t] = s[t] - v;  // exclusive
}

__global__ void scan3_k(int* __restrict__ rowptr, const int* __restrict__ partials,
                        int* __restrict__ fill) {
    int i = blockIdx.x * 256 + threadIdx.x;
    if (i < N_NODES) {
        int r = rowptr[i] + partials[i >> 10];
        rowptr[i] = r;
        fill[i] = r;
    }
    if (i == N_NODES) rowptr[N_NODES] = N_EDGES;
}

__global__ void scatter_k(const int* __restrict__ ei, const float* __restrict__ eattr,
                          int* __restrict__ fill, int* __restrict__ esrc,
                          float* __restrict__ ep) {
    int e = blockIdx.x * 256 + threadIdx.x;
    if (e < N_EDGES) {
        int s = ei[e];
        int d = ei[N_EDGES + e];
        int pos = atomicAdd(&fill[d], 1);
        esrc[pos] = s;
        ep[pos] = eattr[e];
    }
}

// ---------------- Layer-1 aggregation + ELU (wave per node)
__global__ __launch_bounds__(256) void agg1_k(const float* __restrict__ y01,
                                              const float* __restrict__ xr,
                                              const float* __restrict__ b1,
                                              const int* __restrict__ rowptr,
                                              const int* __restrict__ esrc,
                                              const float* __restrict__ ep,
                                              float* __restrict__ x1out) {
    int wave = (blockIdx.x * 256 + threadIdx.x) >> 6;
    int lane = threadIdx.x & 63;
    if (wave >= N_NODES) return;
    int f = lane & 15, slot = lane >> 4;
    int start = rowptr[wave], end = rowptr[wave + 1];
    float acc = 0.f;
    for (int i = start + slot; i < end; i += 4) {
        int s = esrc[i];
        float p = ep[i];
        float a = y01[(size_t)s * 32 + f];
        float b = y01[(size_t)s * 32 + 16 + f];
        acc += (1.f - p) * a + p * b;
    }
    acc += __shfl_xor(acc, 16);
    acc += __shfl_xor(acc, 32);
    int cnt = end - start;
    float agg = acc / fmaxf((float)cnt, 1.f);
    float v = agg + xr[(size_t)wave * 16 + f] + b1[f];
    float x1 = v > 0.f ? v : expm1f(v);
    if (lane < 16) x1out[(size_t)wave * 16 + f] = x1;
}

// ---------------- Layer-2 edge aggregation: U = sum x1[src], V = sum p*x1[src]
__global__ __launch_bounds__(256) void agg2_k(const float* __restrict__ x1,
                                              const int* __restrict__ rowptr,
                                              const int* __restrict__ esrc,
                                              const float* __restrict__ ep,
                                              float* __restrict__ U,
                                              float* __restrict__ V) {
    int wave = (blockIdx.x * 256 + threadIdx.x) >> 6;
    int lane = threadIdx.x & 63;
    if (wave >= N_NODES) return;
    int f = lane & 15, slot = lane >> 4;
    int start = rowptr[wave], end = rowptr[wave + 1];
    float u = 0.f, vv = 0.f;
    for (int i = start + slot; i < end; i += 4) {
        int s = esrc[i];
        float p = ep[i];
        float a = x1[(size_t)s * 16 + f];
        u += a;
        vv += p * a;
    }
    u += __shfl_xor(u, 16);  u += __shfl_xor(u, 32);
    vv += __shfl_xor(vv, 16); vv += __shfl_xor(vv, 32);
    if (lane < 16) {
        U[(size_t)wave * 16 + f] = u;
        V[(size_t)wave * 16 + f] = vv;
    }
}

// ---------------- Final: x2 = ((U-V)@W20 + V@W21)/cnt + x1@root2 + b2; log_softmax
__global__ __launch_bounds__(256) void final_k(const float* __restrict__ x1,
                                               const float* __restrict__ U,
                                               const float* __restrict__ V,
                                               const int* __restrict__ rowptr,
                                               const float* __restrict__ W2,
                                               const float* __restrict__ root2,
                                               const float* __restrict__ b2,
                                               float* __restrict__ out0) {
    int node = (blockIdx.x * 256 + threadIdx.x) >> 6;
    int c = threadIdx.x & 63;
    if (node >= N_NODES) return;
    float val = 0.f;
    if (c < N_CLS) {
        float invc = 1.f / fmaxf((float)(rowptr[node + 1] - rowptr[node]), 1.f);
        float s1 = 0.f, s2 = 0.f;
        size_t base = (size_t)node * 16;
#pragma unroll
        for (int f = 0; f < HID; ++f) {
            float u = U[base + f], vv = V[base + f], xv = x1[base + f];
            s1 += (u - vv) * W2[f * N_CLS + c] + vv * W2[HID * N_CLS + f * N_CLS + c];
            s2 += xv * root2[f * N_CLS + c];
        }
        val = s1 * invc + s2 + b2[c];
    }
    float m = (c < N_CLS) ? val : -INFINITY;
#pragma unroll
    for (int o = 32; o; o >>= 1) m = fmaxf(m, __shfl_xor(m, o));
    float e = (c < N_CLS) ? expf(val - m) : 0.f;
    float ssum = e;
#pragma unroll
    for (int o = 32; o; o >>= 1) ssum += __shfl_xor(ssum, o);
    if (c < N_CLS) out0[(size_t)node * N_CLS + c] = val - m - logf(ssum);
}

extern "C" void kernel_launch(void* const* d_in, const int* in_sizes, int n_in,
                              void* d_out, int out_size, void* d_ws, size_t ws_size,
                              hipStream_t stream) {
    const float* x         = (const float*)d_in[0];
    const int*   ei        = (const int*)d_in[1];     // (2, 3.2M) int32
    const float* eattr     = (const float*)d_in[2];   // (3.2M, 1)
    const float* W1        = (const float*)d_in[3];   // (2,1024,16)
    const float* root1     = (const float*)d_in[4];   // (1024,16)
    const float* b1        = (const float*)d_in[5];   // (16,)
    const float* W2        = (const float*)d_in[6];   // (2,16,40)
    const float* root2     = (const float*)d_in[7];   // (16,40)
    const float* b2        = (const float*)d_in[8];   // (40,)

    float* out0  = (float*)d_out;                       // (100000,40) log_softmax
    float* x1out = (float*)d_out + (size_t)N_NODES * N_CLS;  // (100000,16)

    char* w = (char*)d_ws;
    float* y01    = (float*)w; w += (size_t)N_NODES * 32 * 4;
    float* xr     = (float*)w; w += (size_t)N_NODES * 16 * 4;
    float* U      = (float*)w; w += (size_t)N_NODES * 16 * 4;
    float* V      = (float*)w; w += (size_t)N_NODES * 16 * 4;
    int*   counts = (int*)w;   w += (size_t)N_NODES * 4;
    int*   rowptr = (int*)w;   w += (size_t)(N_NODES + 4) * 4;
    int*   fill   = (int*)w;   w += (size_t)N_NODES * 4;
    int*   parts  = (int*)w;   w += 1024;
    int*   esrc   = (int*)w;   w += (size_t)N_EDGES * 4;
    float* ep     = (float*)w; w += (size_t)N_EDGES * 4;

    const int NB_SCAN = (N_NODES + 1023) / 1024;  // 98

    hipMemsetAsync(counts, 0, N_NODES * sizeof(int), stream);
    gemm1<<<(N_NODES + BM - 1) / BM, 256, 0, stream>>>(x, W1, root1, y01, xr);
    hist_k<<<(N_EDGES + 255) / 256, 256, 0, stream>>>(ei, counts);
    scan1_k<<<NB_SCAN, 256, 0, stream>>>(counts, rowptr, parts);
    scan2_k<<<1, 128, 0, stream>>>(parts, NB_SCAN);
    scan3_k<<<(N_NODES + 256) / 256, 256, 0, stream>>>(rowptr, parts, fill);
    scatter_k<<<(N_EDGES + 255) / 256, 256, 0, stream>>>(ei, eattr, fill, esrc, ep);
    agg1_k<<<(N_NODES * 64 + 255) / 256, 256, 0, stream>>>(y01, xr, b1, rowptr, esrc, ep, x1out);
    agg2_k<<<(N_NODES * 64 + 255) / 256, 256, 0, stream>>>(x1out, rowptr, esrc, ep, U, V);
    final_k<<<(N_NODES * 64 + 255) / 256, 256, 0, stream>>>(x1out, U, V, rowptr, W2, root2, b2, out0);
}